// Round 10
// baseline (619.271 us; speedup 1.0000x reference)
//
#include <hip/hip_runtime.h>
#include <math.h>

#define CCH 64
#define NSP 64
#define TAU 0.25f   // |pivot|^2 threshold for the fast pivot path

// Clobber every AGPR: loop-carried values crossing this point cannot be
// allocated to AGPRs -> the ar[]/ai[] arrays stay in arch VGPRs (no
// v_accvgpr_read/write tax). Empty asm = zero instructions emitted.
#define AGPR_CLOBBER() asm volatile("" ::: \
  "a0","a1","a2","a3","a4","a5","a6","a7","a8","a9","a10","a11","a12","a13","a14","a15", \
  "a16","a17","a18","a19","a20","a21","a22","a23","a24","a25","a26","a27","a28","a29","a30","a31", \
  "a32","a33","a34","a35","a36","a37","a38","a39","a40","a41","a42","a43","a44","a45","a46","a47", \
  "a48","a49","a50","a51","a52","a53","a54","a55","a56","a57","a58","a59","a60","a61","a62","a63", \
  "a64","a65","a66","a67","a68","a69","a70","a71","a72","a73","a74","a75","a76","a77","a78","a79", \
  "a80","a81","a82","a83","a84","a85","a86","a87","a88","a89","a90","a91","a92","a93","a94","a95", \
  "a96","a97","a98","a99","a100","a101","a102","a103","a104","a105","a106","a107","a108","a109","a110","a111", \
  "a112","a113","a114","a115","a116","a117","a118","a119","a120","a121","a122","a123","a124","a125","a126","a127", \
  "a128","a129","a130","a131","a132","a133","a134","a135","a136","a137","a138","a139","a140","a141","a142","a143", \
  "a144","a145","a146","a147","a148","a149","a150","a151","a152","a153","a154","a155","a156","a157","a158","a159", \
  "a160","a161","a162","a163","a164","a165","a166","a167","a168","a169","a170","a171","a172","a173","a174","a175", \
  "a176","a177","a178","a179","a180","a181","a182","a183","a184","a185","a186","a187","a188","a189","a190","a191", \
  "a192","a193","a194","a195","a196","a197","a198","a199","a200","a201","a202","a203","a204","a205","a206","a207", \
  "a208","a209","a210","a211","a212","a213","a214","a215","a216","a217","a218","a219","a220","a221","a222","a223", \
  "a224","a225","a226","a227","a228","a229","a230","a231","a232","a233","a234","a235","a236","a237","a238","a239", \
  "a240","a241","a242","a243","a244","a245","a246","a247","a248","a249","a250","a251","a252","a253","a254","a255")

// ---------------------------------------------------------------------------
// Kernel 1: circular 3x3 conv, per-sample kernels, + bias, + identity kernel.
// (round-1 version; conv is the next target once logdet stops dominating)
// ---------------------------------------------------------------------------
__global__ __launch_bounds__(256) void conv_kernel(
    const float* __restrict__ x, const float* __restrict__ K,
    const float* __restrict__ bias, float* __restrict__ out) {
  int bid = blockIdx.x;            // 0..255
  int b = bid >> 6, co = bid & 63;
  __shared__ float w[CCH * 9];
  __shared__ float tile[64 * 65];
  int t = threadIdx.x;

  for (int i = t; i < CCH * 9; i += 256) {
    float v = K[(size_t)((b * 64 + co) * 64) * 9 + i];
    if (i == co * 9 + 4) v += 1.0f;   // identity: ci==co, kh=kw=1
    w[i] = v;
  }

  int ty = t >> 2;
  int tx = t & 3;
  int x0 = tx << 4;
  float bval = bias[b * 64 + co];
  float acc[16];
#pragma unroll
  for (int i = 0; i < 16; ++i) acc[i] = bval;

  const float* xb = x + (size_t)(b * 64) * 4096;
  for (int ci = 0; ci < 64; ++ci) {
    __syncthreads();
    const float* xc = xb + (size_t)ci * 4096;
#pragma unroll
    for (int j = 0; j < 16; ++j) {
      int i = t + 256 * j;
      tile[(i >> 6) * 65 + (i & 63)] = xc[i];
    }
    __syncthreads();

    float w0 = w[ci * 9 + 0], w1 = w[ci * 9 + 1], w2 = w[ci * 9 + 2];
    float w3 = w[ci * 9 + 3], w4 = w[ci * 9 + 4], w5 = w[ci * 9 + 5];
    float w6 = w[ci * 9 + 6], w7 = w[ci * 9 + 7], w8 = w[ci * 9 + 8];

    int ym = ((ty - 1) & 63) * 65;
    int yc = ty * 65;
    int yp = ((ty + 1) & 63) * 65;
    float in0[18], in1[18], in2[18];
#pragma unroll
    for (int ix = 0; ix < 18; ++ix) {
      int xx = (x0 + ix - 1) & 63;
      in0[ix] = tile[ym + xx];
      in1[ix] = tile[yc + xx];
      in2[ix] = tile[yp + xx];
    }
#pragma unroll
    for (int px = 0; px < 16; ++px) {
      float a = acc[px];
      a = fmaf(w0, in0[px], a); a = fmaf(w1, in0[px + 1], a); a = fmaf(w2, in0[px + 2], a);
      a = fmaf(w3, in1[px], a); a = fmaf(w4, in1[px + 1], a); a = fmaf(w5, in1[px + 2], a);
      a = fmaf(w6, in2[px], a); a = fmaf(w7, in2[px + 1], a); a = fmaf(w8, in2[px + 2], a);
      acc[px] = a;
    }
  }

  float* op = out + (size_t)(b * 64 + co) * 4096 + ty * 64 + x0;
#pragma unroll
  for (int i = 0; i < 16; i += 4) {
    *(float4*)(op + i) = make_float4(acc[i], acc[i + 1], acc[i + 2], acc[i + 3]);
  }
}

// ---------------------------------------------------------------------------
// Kernel 2: per-frequency 64x64 complex LU -> sum log|pivot|.
// One wave per canonical (b,u,v); lane r owns row r, column-compacted.
// Round-10 deltas (instruction diet; structure unchanged from round 7/9):
//  - AGPR_CLOBBER in the k-loop: forces ar/ai into arch VGPRs, killing the
//    v_accvgpr_read/write tax identified from the 46k-instr/wave accounting.
//  - deferred log: pivot lane latches pivmag (cndmask); ONE __logf per lane
//    after the loop instead of a wave-wide logf+divide every step.
//  - v_rcp_f32 via __builtin_amdgcn_rcpf instead of IEEE divide.
//  - chunk-8 guards (halved overshoot).
//  - grid enumerates only the 2050 canonical (u,v): no wasted wave slots.
// ---------------------------------------------------------------------------
__device__ __forceinline__ float rlane(float x, int lane) {
  return __int_as_float(__builtin_amdgcn_readlane(__float_as_int(x), lane));
}

__global__ __launch_bounds__(64, 1) void logdet_kernel(
    const float* __restrict__ K, float* __restrict__ logdet) {
  int bid = blockIdx.x;                      // 0..2049 canonical reps
  int u, v;
  if (bid < 33) { u = 0; v = bid; }
  else if (bid < 2017) { int q = bid - 33; u = 1 + (q >> 6); v = q & 63; }
  else { u = 32; v = bid - 2017; }
  // self-paired keys (u,v both in {0,32}) weight 1, else 2
  float weight = (((u & 31) == 0) && ((v & 31) == 0)) ? 1.0f : 2.0f;
  int b = blockIdx.y;

  int r = threadIdx.x;                       // lane == matrix row

  // twiddles w[kh*3+kw] = e^{-2*pi*i*(u*kh+v*kw)/64} via complex power products
  float Ar[3], Ai[3], Br[3], Bi[3];
  {
    const float k2pi = -6.283185307179586f / 64.0f;
    float su, cu, sv, cv;
    __sincosf(k2pi * (float)u, &su, &cu);
    __sincosf(k2pi * (float)v, &sv, &cv);
    Ar[0] = 1.0f; Ai[0] = 0.0f; Ar[1] = cu; Ai[1] = su;
    Ar[2] = cu * cu - su * su; Ai[2] = 2.0f * cu * su;
    Br[0] = 1.0f; Bi[0] = 0.0f; Br[1] = cv; Bi[1] = sv;
    Br[2] = cv * cv - sv * sv; Bi[2] = 2.0f * cv * sv;
  }
  float wr[9], wi[9];
#pragma unroll
  for (int kh = 0; kh < 3; ++kh)
#pragma unroll
    for (int kw = 0; kw < 3; ++kw) {
      wr[kh * 3 + kw] = Ar[kh] * Br[kw] - Ai[kh] * Bi[kw];
      wi[kh * 3 + kw] = Ar[kh] * Bi[kw] + Ai[kh] * Br[kw];
    }

  // Build row r of Khat with aligned float4 loads (row = 576 floats)
  float ar[65], ai[65];
  const float4* Kp4 = (const float4*)(K + (size_t)(b * 64 + r) * 576);
#pragma unroll
  for (int g = 0; g < 16; ++g) {             // 16 groups x 4 columns
    AGPR_CLOBBER();
    float f[36];
#pragma unroll
    for (int qq = 0; qq < 9; ++qq) {
      float4 vv = Kp4[g * 9 + qq];
      f[qq * 4 + 0] = vv.x; f[qq * 4 + 1] = vv.y; f[qq * 4 + 2] = vv.z; f[qq * 4 + 3] = vv.w;
    }
#pragma unroll
    for (int cc = 0; cc < 4; ++cc) {
      int c = g * 4 + cc;
      float re = 0.0f, im = 0.0f;
#pragma unroll
      for (int t9 = 0; t9 < 9; ++t9) {
        float kv = f[cc * 9 + t9];
        re = fmaf(kv, wr[t9], re);
        im = fmaf(kv, wi[t9], im);
      }
      if (c == r) { re += wr[4]; im += wi[4]; }  // identity: center-tap delta
      ar[c] = re; ai[c] = im;
    }
  }
  ar[64] = 0.0f; ai[64] = 0.0f;              // pad slot for chunk overshoot

  bool active = true;
  float pivmag = 1.0f;                       // each lane's own pivot |.|^2

  for (int k = 0; k < 63; ++k) {
    AGPR_CLOBBER();                          // keep arrays in arch VGPRs
    float mag = fmaf(ar[0], ar[0], ai[0] * ai[0]);
    bool cand = active && (mag >= TAU);
    unsigned long long candm = __ballot(cand);
    int p;
    if (candm != 0ULL) {
      p = __ffsll(candm) - 1;                // fast path: first big-enough pivot
    } else {                                 // rare: all remaining pivots tiny
      float mm = active ? mag : -1.0f;
#pragma unroll
      for (int off = 32; off > 0; off >>= 1) mm = fmaxf(mm, __shfl_xor(mm, off));
      unsigned long long mx = __ballot(active && (mag == mm));
      if (mx == 0ULL) mx = __ballot(active); // degenerate (NaN) guard
      p = __ffsll(mx) - 1;
    }
    p = __builtin_amdgcn_readfirstlane(p) & 63;  // uniform, always-valid lane

    bool isPiv = (r == p);
    pivmag = isPiv ? mag : pivmag;           // latch; log deferred to the end
    active = active && !isPiv;

    float pr = rlane(ar[0], p);
    float pi = rlane(ai[0], p);
    float inv = __builtin_amdgcn_rcpf(fmaf(pr, pr, pi * pi));
    float fre = (ar[0] * pr + ai[0] * pi) * inv;
    float fim = (ai[0] * pr - ar[0] * pi) * inv;
    fre = active ? fre : 0.0f;               // pivot + retired lanes: shift-only
    fim = active ? fim : 0.0f;

    int rem = 63 - k;                        // remaining columns at indices 1..rem
#pragma unroll
    for (int ch = 0; ch < 8; ++ch) {
      if (ch * 8 < rem) {                    // uniform scalar guard, chunk=8
        int c0 = ch * 8 + 1;
        float lrA[8], liA[8];
#pragma unroll
        for (int e = 0; e < 8; ++e) {
          lrA[e] = rlane(ar[c0 + e], p);
          liA[e] = rlane(ai[c0 + e], p);
        }
#pragma unroll
        for (int e = 0; e < 8; ++e) {
          int c = c0 + e;
          ar[c - 1] = fmaf(fim, liA[e], fmaf(-fre, lrA[e], ar[c]));
          ai[c - 1] = fmaf(-fim, lrA[e], fmaf(-fre, liA[e], ai[c]));
        }
      }
    }
  }
  if (active) pivmag = fmaf(ar[0], ar[0], ai[0] * ai[0]);  // last surviving row

  float logsum = 0.5f * __logf(pivmag);      // one log per lane, total = logdet
#pragma unroll
  for (int off = 32; off > 0; off >>= 1) logsum += __shfl_xor(logsum, off);
  if (r == 0) atomicAdd(&logdet[b], weight * logsum);
}

// ---------------------------------------------------------------------------
extern "C" void kernel_launch(void* const* d_in, const int* in_sizes, int n_in,
                              void* d_out, int out_size, void* d_ws, size_t ws_size,
                              hipStream_t stream) {
  const float* conv_in = (const float*)d_in[0];   // [4,64,64,64]
  const float* K       = (const float*)d_in[1];   // [4,64,64,3,3]
  const float* bias    = (const float*)d_in[2];   // [4,64,1,1]
  float* out = (float*)d_out;                     // conv_out (1048576) ++ logdet (4)
  float* logdet = out + 1048576;

  hipMemsetAsync(logdet, 0, 4 * sizeof(float), stream);
  conv_kernel<<<dim3(256), dim3(256), 0, stream>>>(conv_in, K, bias, out);
  logdet_kernel<<<dim3(2050, 4), dim3(64), 0, stream>>>(K, logdet);
}

// Round 11
// 371.741 us; speedup vs baseline: 1.6659x; 1.6659x over previous
//
#include <hip/hip_runtime.h>
#include <hip/hip_fp16.h>
#include <math.h>

#define CCH 64
#define NSP 64
#define TAU 0.5f   // |pivot|^2 threshold (f32) for the fast pivot path

// ---------------------------------------------------------------------------
// Kernel 1: circular 3x3 conv, per-sample kernels, + bias, + identity kernel.
// (round-1 version; revisit once logdet stops dominating)
// ---------------------------------------------------------------------------
__global__ __launch_bounds__(256) void conv_kernel(
    const float* __restrict__ x, const float* __restrict__ K,
    const float* __restrict__ bias, float* __restrict__ out) {
  int bid = blockIdx.x;            // 0..255
  int b = bid >> 6, co = bid & 63;
  __shared__ float w[CCH * 9];
  __shared__ float tile[64 * 65];
  int t = threadIdx.x;

  for (int i = t; i < CCH * 9; i += 256) {
    float v = K[(size_t)((b * 64 + co) * 64) * 9 + i];
    if (i == co * 9 + 4) v += 1.0f;   // identity: ci==co, kh=kw=1
    w[i] = v;
  }

  int ty = t >> 2;
  int tx = t & 3;
  int x0 = tx << 4;
  float bval = bias[b * 64 + co];
  float acc[16];
#pragma unroll
  for (int i = 0; i < 16; ++i) acc[i] = bval;

  const float* xb = x + (size_t)(b * 64) * 4096;
  for (int ci = 0; ci < 64; ++ci) {
    __syncthreads();
    const float* xc = xb + (size_t)ci * 4096;
#pragma unroll
    for (int j = 0; j < 16; ++j) {
      int i = t + 256 * j;
      tile[(i >> 6) * 65 + (i & 63)] = xc[i];
    }
    __syncthreads();

    float w0 = w[ci * 9 + 0], w1 = w[ci * 9 + 1], w2 = w[ci * 9 + 2];
    float w3 = w[ci * 9 + 3], w4 = w[ci * 9 + 4], w5 = w[ci * 9 + 5];
    float w6 = w[ci * 9 + 6], w7 = w[ci * 9 + 7], w8 = w[ci * 9 + 8];

    int ym = ((ty - 1) & 63) * 65;
    int yc = ty * 65;
    int yp = ((ty + 1) & 63) * 65;
    float in0[18], in1[18], in2[18];
#pragma unroll
    for (int ix = 0; ix < 18; ++ix) {
      int xx = (x0 + ix - 1) & 63;
      in0[ix] = tile[ym + xx];
      in1[ix] = tile[yc + xx];
      in2[ix] = tile[yp + xx];
    }
#pragma unroll
    for (int px = 0; px < 16; ++px) {
      float a = acc[px];
      a = fmaf(w0, in0[px], a); a = fmaf(w1, in0[px + 1], a); a = fmaf(w2, in0[px + 2], a);
      a = fmaf(w3, in1[px], a); a = fmaf(w4, in1[px + 1], a); a = fmaf(w5, in1[px + 2], a);
      a = fmaf(w6, in2[px], a); a = fmaf(w7, in2[px + 1], a); a = fmaf(w8, in2[px + 2], a);
      acc[px] = a;
    }
  }

  float* op = out + (size_t)(b * 64 + co) * 4096 + ty * 64 + x0;
#pragma unroll
  for (int i = 0; i < 16; i += 4) {
    *(float4*)(op + i) = make_float4(acc[i], acc[i + 1], acc[i + 2], acc[i + 3]);
  }
}

// ---------------------------------------------------------------------------
// Kernel 2: per-frequency 64x64 complex LU -> sum log|pivot|.
// One wave per canonical (b,u,v); lane r owns row r, column-compacted so the
// pivot column is always register slot 0. Round-11 delta: matrix stored as
// PACKED f16x2 (re,im in one VGPR per column):
//  - 1 readlane per element instead of 2 (readlane ~quarter-rate is the
//    measured bottleneck: r6/r9/r10 cycle accounting),
//  - complex update = 2 v_pk_fma_f16 (SGPR B-operand) instead of 4 fp32 FMA,
//  - 65-reg matrix -> no AGPR parking, ~110 total regs, 3 waves/SIMD.
// Pivot magnitudes, multipliers, and logs stay fp32. TAU=0.5 bounds growth.
// ---------------------------------------------------------------------------
__device__ __forceinline__ int h2i(__half2 h) { int i; __builtin_memcpy(&i, &h, 4); return i; }
__device__ __forceinline__ __half2 i2h(int i) { __half2 h; __builtin_memcpy(&h, &i, 4); return h; }

__global__ __launch_bounds__(64, 3) void logdet_kernel(
    const float* __restrict__ K, float* __restrict__ logdet) {
  int bid = blockIdx.x;                      // 0..2049 canonical reps
  int u, v;
  if (bid < 33) { u = 0; v = bid; }
  else if (bid < 2017) { int q = bid - 33; u = 1 + (q >> 6); v = q & 63; }
  else { u = 32; v = bid - 2017; }
  float weight = (((u & 31) == 0) && ((v & 31) == 0)) ? 1.0f : 2.0f;
  int b = blockIdx.y;

  int r = threadIdx.x;                       // lane == matrix row

  // twiddles w[kh*3+kw] = e^{-2*pi*i*(u*kh+v*kw)/64} via complex power products
  float Ar[3], Ai[3], Br[3], Bi[3];
  {
    const float k2pi = -6.283185307179586f / 64.0f;
    float su, cu, sv, cv;
    __sincosf(k2pi * (float)u, &su, &cu);
    __sincosf(k2pi * (float)v, &sv, &cv);
    Ar[0] = 1.0f; Ai[0] = 0.0f; Ar[1] = cu; Ai[1] = su;
    Ar[2] = cu * cu - su * su; Ai[2] = 2.0f * cu * su;
    Br[0] = 1.0f; Bi[0] = 0.0f; Br[1] = cv; Bi[1] = sv;
    Br[2] = cv * cv - sv * sv; Bi[2] = 2.0f * cv * sv;
  }
  float wr[9], wi[9];
#pragma unroll
  for (int kh = 0; kh < 3; ++kh)
#pragma unroll
    for (int kw = 0; kw < 3; ++kw) {
      wr[kh * 3 + kw] = Ar[kh] * Br[kw] - Ai[kh] * Bi[kw];
      wi[kh * 3 + kw] = Ar[kh] * Bi[kw] + Ai[kh] * Br[kw];
    }

  // Build row r of Khat in fp32, pack each column to f16x2 immediately.
  __half2 a2[65];
  const float4* Kp4 = (const float4*)(K + (size_t)(b * 64 + r) * 576);
#pragma unroll
  for (int g = 0; g < 16; ++g) {             // 16 groups x 4 columns
    float f[36];
#pragma unroll
    for (int qq = 0; qq < 9; ++qq) {
      float4 vv = Kp4[g * 9 + qq];
      f[qq * 4 + 0] = vv.x; f[qq * 4 + 1] = vv.y; f[qq * 4 + 2] = vv.z; f[qq * 4 + 3] = vv.w;
    }
#pragma unroll
    for (int cc = 0; cc < 4; ++cc) {
      int c = g * 4 + cc;
      float re = 0.0f, im = 0.0f;
#pragma unroll
      for (int t9 = 0; t9 < 9; ++t9) {
        float kv = f[cc * 9 + t9];
        re = fmaf(kv, wr[t9], re);
        im = fmaf(kv, wi[t9], im);
      }
      if (c == r) { re += wr[4]; im += wi[4]; }  // identity: center-tap delta
      a2[c] = __floats2half2_rn(re, im);
    }
  }
  a2[64] = __floats2half2_rn(0.0f, 0.0f);    // pad slot for chunk overshoot

  bool active = true;
  float pivmag = 1.0f;                       // each lane's own pivot |.|^2 (f32)

  for (int k = 0; k < 63; ++k) {
    float fr0 = __low2float(a2[0]);
    float fi0 = __high2float(a2[0]);
    float mag = fmaf(fr0, fr0, fi0 * fi0);
    bool cand = active && (mag >= TAU);
    unsigned long long candm = __ballot(cand);
    int p;
    if (candm != 0ULL) {
      p = __ffsll(candm) - 1;                // fast path: first big-enough pivot
    } else {                                 // rare: all remaining pivots tiny
      float mm = active ? mag : -1.0f;
#pragma unroll
      for (int off = 32; off > 0; off >>= 1) mm = fmaxf(mm, __shfl_xor(mm, off));
      unsigned long long mx = __ballot(active && (mag == mm));
      if (mx == 0ULL) mx = __ballot(active); // degenerate (NaN) guard
      p = __ffsll(mx) - 1;
    }
    p = __builtin_amdgcn_readfirstlane(p) & 63;  // uniform, always-valid lane

    bool isPiv = (r == p);
    pivmag = isPiv ? mag : pivmag;           // latch; log deferred to the end
    active = active && !isPiv;

    __half2 pivh = i2h(__builtin_amdgcn_readlane(h2i(a2[0]), p));
    float pr = __low2float(pivh);
    float pi = __high2float(pivh);
    float inv = __builtin_amdgcn_rcpf(fmaf(pr, pr, pi * pi));
    float fre = (fr0 * pr + fi0 * pi) * inv;
    float fim = (fi0 * pr - fr0 * pi) * inv;
    fre = active ? fre : 0.0f;               // pivot + retired lanes: shift-only
    fim = active ? fim : 0.0f;
    __half2 nfre2 = __float2half2_rn(-fre);                     // (-fre, -fre)
    __half2 fim2 = __halves2half2(__float2half_rn(fim),
                                  __float2half_rn(-fim));       // (fim, -fim)

    int rem = 63 - k;                        // remaining columns at slots 1..rem
#pragma unroll
    for (int ch = 0; ch < 8; ++ch) {
      if (ch * 8 < rem) {                    // uniform scalar guard, chunk=8
        int c0 = ch * 8 + 1;
        int Li[8];
#pragma unroll
        for (int e = 0; e < 8; ++e)          // batch: 8 readlanes (packed rows)
          Li[e] = __builtin_amdgcn_readlane(h2i(a2[c0 + e]), p);
#pragma unroll
        for (int e = 0; e < 8; ++e) {
          __half2 P = i2h(Li[e]);
          // (re',im') = (re,im) - fre*(lr,li) + fim*(li,-lr): 2 pk_fma
          __half2 tmp = __hfma2(nfre2, P, a2[c0 + e]);
          a2[c0 + e - 1] = __hfma2(fim2, __lowhigh2highlow(P), tmp);
        }
      }
    }
  }
  {
    float fr0 = __low2float(a2[0]);
    float fi0 = __high2float(a2[0]);
    if (active) pivmag = fmaf(fr0, fr0, fi0 * fi0);  // last surviving row
  }

  float logsum = 0.5f * __logf(pivmag);      // one log per lane; sum = logdet
#pragma unroll
  for (int off = 32; off > 0; off >>= 1) logsum += __shfl_xor(logsum, off);
  if (r == 0) atomicAdd(&logdet[b], weight * logsum);
}

// ---------------------------------------------------------------------------
extern "C" void kernel_launch(void* const* d_in, const int* in_sizes, int n_in,
                              void* d_out, int out_size, void* d_ws, size_t ws_size,
                              hipStream_t stream) {
  const float* conv_in = (const float*)d_in[0];   // [4,64,64,64]
  const float* K       = (const float*)d_in[1];   // [4,64,64,3,3]
  const float* bias    = (const float*)d_in[2];   // [4,64,1,1]
  float* out = (float*)d_out;                     // conv_out (1048576) ++ logdet (4)
  float* logdet = out + 1048576;

  hipMemsetAsync(logdet, 0, 4 * sizeof(float), stream);
  conv_kernel<<<dim3(256), dim3(256), 0, stream>>>(conv_in, K, bias, out);
  logdet_kernel<<<dim3(2050, 4), dim3(64), 0, stream>>>(K, logdet);
}

// Round 12
// 337.073 us; speedup vs baseline: 1.8372x; 1.1028x over previous
//
#include <hip/hip_runtime.h>
#include <hip/hip_fp16.h>
#include <math.h>

#define TAU 0.5f   // |pivot|^2 threshold (f32) for the fast pivot path

// ---------------------------------------------------------------------------
// Fused kernel: 2306 blocks x 256 threads.
//   bid % 9 == 8 (bid<2304)  -> conv block  cid = bid/9        (256 blocks)
//   else                     -> logdet block, key = lid        (2050 blocks)
// Interleaving spreads conv's memory/LDS work through the dispatch so it
// hides in logdet's idle issue slots (logdet alone: VALUBusy 64%).
// Both paths are register-light (84 / ~90 VGPR) -- the round-3 fusion spill
// came from the 130-float fp32 LU + tight launch bounds, both gone now.
//
// conv: circular 3x3, per-sample kernels + bias + identity (round-1 body).
// logdet: per-frequency 64x64 complex LU, f16x2-packed columns (round-11
// body); each of the 4 waves handles one batch b for the block's key.
// No barriers in the logdet path; conv's __syncthreads are block-uniform.
// ---------------------------------------------------------------------------
__device__ __forceinline__ int h2i(__half2 h) { int i; __builtin_memcpy(&i, &h, 4); return i; }
__device__ __forceinline__ __half2 i2h(int i) { __half2 h; __builtin_memcpy(&h, &i, 4); return h; }

__global__ __launch_bounds__(256, 2) void fused_kernel(
    const float* __restrict__ x, const float* __restrict__ K,
    const float* __restrict__ bias, float* __restrict__ out,
    float* __restrict__ logdet) {
  __shared__ float smem[4736];               // conv: w[576] + tile[64*65]
  int bid = blockIdx.x;
  int t = threadIdx.x;

  bool isConv = false;
  int cid = 0, lid = 0;
  if (bid < 2304) {
    int q9 = bid / 9, m9 = bid - q9 * 9;
    if (m9 == 8) { isConv = true; cid = q9; }
    else lid = bid - (bid + 1) / 9;          // 0..2047
  } else {
    lid = bid - 256;                         // 2048, 2049
  }

  if (isConv) {
    // ================= conv =================
    int b = cid >> 6, co = cid & 63;
    float* w = smem;                         // 576
    float* tile = smem + 576;                // 64*65

    for (int i = t; i < 576; i += 256) {
      float vv = K[(size_t)((b * 64 + co) * 64) * 9 + i];
      if (i == co * 9 + 4) vv += 1.0f;       // identity: ci==co, center tap
      w[i] = vv;
    }

    int ty = t >> 2;
    int tx = t & 3;
    int x0 = tx << 4;
    float bval = bias[b * 64 + co];
    float acc[16];
#pragma unroll
    for (int i = 0; i < 16; ++i) acc[i] = bval;

    const float* xb = x + (size_t)(b * 64) * 4096;
    for (int ci = 0; ci < 64; ++ci) {
      __syncthreads();                       // WAR on tile (and w on first iter)
      const float* xc = xb + (size_t)ci * 4096;
#pragma unroll
      for (int j = 0; j < 16; ++j) {
        int i = t + 256 * j;
        tile[(i >> 6) * 65 + (i & 63)] = xc[i];
      }
      __syncthreads();

      float w0 = w[ci * 9 + 0], w1 = w[ci * 9 + 1], w2 = w[ci * 9 + 2];
      float w3 = w[ci * 9 + 3], w4 = w[ci * 9 + 4], w5 = w[ci * 9 + 5];
      float w6 = w[ci * 9 + 6], w7 = w[ci * 9 + 7], w8 = w[ci * 9 + 8];

      int ym = ((ty - 1) & 63) * 65;
      int yc = ty * 65;
      int yp = ((ty + 1) & 63) * 65;
      float in0[18], in1[18], in2[18];
#pragma unroll
      for (int ix = 0; ix < 18; ++ix) {
        int xx = (x0 + ix - 1) & 63;
        in0[ix] = tile[ym + xx];
        in1[ix] = tile[yc + xx];
        in2[ix] = tile[yp + xx];
      }
#pragma unroll
      for (int px = 0; px < 16; ++px) {
        float a = acc[px];
        a = fmaf(w0, in0[px], a); a = fmaf(w1, in0[px + 1], a); a = fmaf(w2, in0[px + 2], a);
        a = fmaf(w3, in1[px], a); a = fmaf(w4, in1[px + 1], a); a = fmaf(w5, in1[px + 2], a);
        a = fmaf(w6, in2[px], a); a = fmaf(w7, in2[px + 1], a); a = fmaf(w8, in2[px + 2], a);
        acc[px] = a;
      }
    }

    float* op = out + (size_t)(b * 64 + co) * 4096 + ty * 64 + x0;
#pragma unroll
    for (int i = 0; i < 16; i += 4) {
      *(float4*)(op + i) = make_float4(acc[i], acc[i + 1], acc[i + 2], acc[i + 3]);
    }
    return;
  }

  // ================= logdet =================
  int u, v;
  if (lid < 33) { u = 0; v = lid; }
  else if (lid < 2017) { int q = lid - 33; u = 1 + (q >> 6); v = q & 63; }
  else { u = 32; v = lid - 2017; }
  float weight = (((u & 31) == 0) && ((v & 31) == 0)) ? 1.0f : 2.0f;

  int b = t >> 6;                            // wave id == batch
  int r = t & 63;                            // lane == matrix row

  // twiddles w[kh*3+kw] = e^{-2*pi*i*(u*kh+v*kw)/64} via complex power products
  float Ar[3], Ai[3], Br[3], Bi[3];
  {
    const float k2pi = -6.283185307179586f / 64.0f;
    float su, cu, sv, cv;
    __sincosf(k2pi * (float)u, &su, &cu);
    __sincosf(k2pi * (float)v, &sv, &cv);
    Ar[0] = 1.0f; Ai[0] = 0.0f; Ar[1] = cu; Ai[1] = su;
    Ar[2] = cu * cu - su * su; Ai[2] = 2.0f * cu * su;
    Br[0] = 1.0f; Bi[0] = 0.0f; Br[1] = cv; Bi[1] = sv;
    Br[2] = cv * cv - sv * sv; Bi[2] = 2.0f * cv * sv;
  }
  float wr[9], wi[9];
#pragma unroll
  for (int kh = 0; kh < 3; ++kh)
#pragma unroll
    for (int kw = 0; kw < 3; ++kw) {
      wr[kh * 3 + kw] = Ar[kh] * Br[kw] - Ai[kh] * Bi[kw];
      wi[kh * 3 + kw] = Ar[kh] * Bi[kw] + Ai[kh] * Br[kw];
    }

  // Build row r of Khat in fp32, pack each column to f16x2 immediately.
  __half2 a2[65];
  const float4* Kp4 = (const float4*)(K + (size_t)(b * 64 + r) * 576);
#pragma unroll
  for (int g = 0; g < 16; ++g) {             // 16 groups x 4 columns
    float f[36];
#pragma unroll
    for (int qq = 0; qq < 9; ++qq) {
      float4 vv = Kp4[g * 9 + qq];
      f[qq * 4 + 0] = vv.x; f[qq * 4 + 1] = vv.y; f[qq * 4 + 2] = vv.z; f[qq * 4 + 3] = vv.w;
    }
#pragma unroll
    for (int cc = 0; cc < 4; ++cc) {
      int c = g * 4 + cc;
      float re = 0.0f, im = 0.0f;
#pragma unroll
      for (int t9 = 0; t9 < 9; ++t9) {
        float kv = f[cc * 9 + t9];
        re = fmaf(kv, wr[t9], re);
        im = fmaf(kv, wi[t9], im);
      }
      if (c == r) { re += wr[4]; im += wi[4]; }  // identity: center-tap delta
      a2[c] = __floats2half2_rn(re, im);
    }
  }
  a2[64] = __floats2half2_rn(0.0f, 0.0f);    // pad slot for chunk overshoot

  bool active = true;
  float pivmag = 1.0f;                       // each lane's own pivot |.|^2 (f32)

  for (int k = 0; k < 63; ++k) {
    float fr0 = __low2float(a2[0]);
    float fi0 = __high2float(a2[0]);
    float mag = fmaf(fr0, fr0, fi0 * fi0);
    bool cand = active && (mag >= TAU);
    unsigned long long candm = __ballot(cand);
    int p;
    if (candm != 0ULL) {
      p = __ffsll(candm) - 1;                // fast path: first big-enough pivot
    } else {                                 // rare: all remaining pivots tiny
      float mm = active ? mag : -1.0f;
#pragma unroll
      for (int off = 32; off > 0; off >>= 1) mm = fmaxf(mm, __shfl_xor(mm, off));
      unsigned long long mx = __ballot(active && (mag == mm));
      if (mx == 0ULL) mx = __ballot(active); // degenerate (NaN) guard
      p = __ffsll(mx) - 1;
    }
    p = __builtin_amdgcn_readfirstlane(p) & 63;  // uniform, always-valid lane

    bool isPiv = (r == p);
    pivmag = isPiv ? mag : pivmag;           // latch; log deferred to the end
    active = active && !isPiv;

    __half2 pivh = i2h(__builtin_amdgcn_readlane(h2i(a2[0]), p));
    float pr = __low2float(pivh);
    float pi = __high2float(pivh);
    float inv = __builtin_amdgcn_rcpf(fmaf(pr, pr, pi * pi));
    float fre = (fr0 * pr + fi0 * pi) * inv;
    float fim = (fi0 * pr - fr0 * pi) * inv;
    fre = active ? fre : 0.0f;               // pivot + retired lanes: shift-only
    fim = active ? fim : 0.0f;
    __half2 nfre2 = __float2half2_rn(-fre);                     // (-fre, -fre)
    __half2 fim2 = __halves2half2(__float2half_rn(fim),
                                  __float2half_rn(-fim));       // (fim, -fim)

    int rem = 63 - k;                        // remaining columns at slots 1..rem
#pragma unroll
    for (int ch = 0; ch < 8; ++ch) {
      if (ch * 8 < rem) {                    // uniform scalar guard, chunk=8
        int c0 = ch * 8 + 1;
        int Li[8];
#pragma unroll
        for (int e = 0; e < 8; ++e)          // batch: 8 readlanes (packed rows)
          Li[e] = __builtin_amdgcn_readlane(h2i(a2[c0 + e]), p);
#pragma unroll
        for (int e = 0; e < 8; ++e) {
          __half2 P = i2h(Li[e]);
          // (re',im') = (re,im) - fre*(lr,li) + fim*(li,-lr): 2 pk_fma
          __half2 tmp = __hfma2(nfre2, P, a2[c0 + e]);
          a2[c0 + e - 1] = __hfma2(fim2, __lowhigh2highlow(P), tmp);
        }
      }
    }
  }
  {
    float fr0 = __low2float(a2[0]);
    float fi0 = __high2float(a2[0]);
    if (active) pivmag = fmaf(fr0, fr0, fi0 * fi0);  // last surviving row
  }

  float logsum = 0.5f * __logf(pivmag);      // one log per lane; sum = logdet
#pragma unroll
  for (int off = 32; off > 0; off >>= 1) logsum += __shfl_xor(logsum, off);
  if (r == 0) atomicAdd(&logdet[b], weight * logsum);
}

// ---------------------------------------------------------------------------
extern "C" void kernel_launch(void* const* d_in, const int* in_sizes, int n_in,
                              void* d_out, int out_size, void* d_ws, size_t ws_size,
                              hipStream_t stream) {
  const float* conv_in = (const float*)d_in[0];   // [4,64,64,64]
  const float* K       = (const float*)d_in[1];   // [4,64,64,3,3]
  const float* bias    = (const float*)d_in[2];   // [4,64,1,1]
  float* out = (float*)d_out;                     // conv_out (1048576) ++ logdet (4)
  float* logdet = out + 1048576;

  hipMemsetAsync(logdet, 0, 4 * sizeof(float), stream);
  fused_kernel<<<dim3(2306), dim3(256), 0, stream>>>(conv_in, K, bias, out, logdet);
}